// Round 1
// baseline (743.600 us; speedup 1.0000x reference)
//
#include <hip/hip_runtime.h>
#include <hip/hip_bf16.h>
#include <cstdint>
#include <cstddef>

#define N_TOK 16384
#define DIM   1024
#define NEXP  64
#define CAPACITY 640

typedef __bf16 bf16x8 __attribute__((ext_vector_type(8)));
typedef float  f32x4  __attribute__((ext_vector_type(4)));

__device__ __forceinline__ unsigned short f2bf(float f) {
    union { float f; unsigned int u; } a; a.f = f;
    unsigned int r = a.u + 0x7FFFu + ((a.u >> 16) & 1u);  // RTNE
    return (unsigned short)(r >> 16);
}

// ---------------------------------------------------------------------------
// Phase 1: router GEMM (fp32) + top-2 + softmax gates + x -> bf16 conversion.
// Block = 256 threads handles 64 tokens x 64 experts. K-tiled by 64.
// ---------------------------------------------------------------------------
__global__ __launch_bounds__(256) void router_kernel(
    const float* __restrict__ x, const float* __restrict__ Wr,
    const float* __restrict__ br, unsigned short* __restrict__ xb,
    int* __restrict__ top2i, float* __restrict__ gates2)
{
    __shared__ float xs[64][68];   // [token][k] fp32 tile (pad 68 vs bank conflicts)
    __shared__ float wT[64][68];   // [expert][k] transposed Wr tile
    const int tid = threadIdx.x;
    const int t0  = blockIdx.x * 64;
    const int tm  = tid >> 4;     // 0..15 token group
    const int te  = tid & 15;     // 0..15 expert group

    float acc[4][4];
#pragma unroll
    for (int i = 0; i < 4; i++)
#pragma unroll
        for (int j = 0; j < 4; j++) acc[i][j] = 0.f;

    for (int ks = 0; ks < DIM; ks += 64) {
        __syncthreads();
        // stage x tile (and emit bf16 copy of x while it's in registers)
#pragma unroll
        for (int l = 0; l < 4; l++) {
            int row = l * 16 + tm;
            int col = te * 4;
            float4 v = *(const float4*)(x + (size_t)(t0 + row) * DIM + ks + col);
            *(float4*)&xs[row][col] = v;
            ushort4 b = make_ushort4(f2bf(v.x), f2bf(v.y), f2bf(v.z), f2bf(v.w));
            *(ushort4*)(xb + (size_t)(t0 + row) * DIM + ks + col) = b;
        }
        // stage Wr tile transposed: wT[e][k]
#pragma unroll
        for (int l = 0; l < 4; l++) {
            int kr = l * 16 + tm;
            int ec = te * 4;
            float4 v = *(const float4*)(Wr + (size_t)(ks + kr) * NEXP + ec);
            wT[ec + 0][kr] = v.x; wT[ec + 1][kr] = v.y;
            wT[ec + 2][kr] = v.z; wT[ec + 3][kr] = v.w;
        }
        __syncthreads();
#pragma unroll 4
        for (int kk = 0; kk < 64; kk += 4) {
            float4 xv[4], wv[4];
#pragma unroll
            for (int i = 0; i < 4; i++) xv[i] = *(float4*)&xs[tm + i * 16][kk];
#pragma unroll
            for (int j = 0; j < 4; j++) wv[j] = *(float4*)&wT[te + j * 16][kk];
#pragma unroll
            for (int i = 0; i < 4; i++)
#pragma unroll
                for (int j = 0; j < 4; j++)
                    acc[i][j] += xv[i].x * wv[j].x + xv[i].y * wv[j].y +
                                 xv[i].z * wv[j].z + xv[i].w * wv[j].w;
        }
    }
    __syncthreads();
    // dump logits (+bias) into xs, then one thread per token does top-2
#pragma unroll
    for (int i = 0; i < 4; i++)
#pragma unroll
        for (int j = 0; j < 4; j++)
            xs[tm + i * 16][te + j * 16] = acc[i][j] + br[te + j * 16];
    __syncthreads();
    if (tid < 64) {
        int n = t0 + tid;
        float v1 = -1e30f, v2 = -1e30f; int i1 = 0, i2 = 0;
        for (int e = 0; e < 64; e++) {
            float v = xs[tid][e];
            if (v > v1)      { v2 = v1; i2 = i1; v1 = v; i1 = e; }
            else if (v > v2) { v2 = v;  i2 = e; }
        }
        float g0 = 1.f / (1.f + expf(v2 - v1));   // softmax over (v1,v2), v1>=v2
        top2i[n * 2 + 0] = i1; top2i[n * 2 + 1] = i2;
        gates2[n * 2 + 0] = g0; gates2[n * 2 + 1] = 1.f - g0;
    }
}

// ---------------------------------------------------------------------------
// Phase 2a: per-chunk expert histograms. Position p = k*N + n (k-major order,
// matching the reference's transpose(1,0).flatten() + cumsum semantics).
// ---------------------------------------------------------------------------
__global__ __launch_bounds__(256) void hist_kernel(
    const int* __restrict__ top2i, int* __restrict__ hist)
{
    __shared__ int cnt[NEXP];
    int tid = threadIdx.x;
    if (tid < NEXP) cnt[tid] = 0;
    __syncthreads();
    int p = blockIdx.x * 256 + tid;
    int k = p >> 14, n = p & 16383;
    int e = top2i[n * 2 + k];
    atomicAdd(&cnt[e], 1);
    __syncthreads();
    if (tid < NEXP) hist[blockIdx.x * NEXP + tid] = cnt[tid];
}

// Phase 2b: exclusive scan over chunks per expert + clamped totals.
__global__ __launch_bounds__(64) void scan_kernel(
    const int* __restrict__ hist, int* __restrict__ pre, int* __restrict__ cntc)
{
    int e = threadIdx.x;
    int run = 0;
#pragma unroll 8
    for (int c = 0; c < 128; c++) {
        pre[c * NEXP + e] = run;
        run += hist[c * NEXP + e];
    }
    cntc[e] = run < CAPACITY ? run : CAPACITY;
}

// Phase 2c: stable intra-chunk ranks via wave ballot; build per-expert lists.
__global__ __launch_bounds__(64) void rank_kernel(
    const int* __restrict__ top2i, const float* __restrict__ gates2,
    const int* __restrict__ pre, int* __restrict__ list_tok,
    float* __restrict__ list_gate)
{
    int lane = threadIdx.x;
    int c = blockIdx.x;
    int cnt_reg = pre[c * NEXP + lane];            // lane e owns expert e's counter
    unsigned long long below = (1ull << lane) - 1ull;
    for (int r = 0; r < 4; r++) {                  // 4 x 64 = 256 positions, in order
        int p = c * 256 + r * 64 + lane;
        int k = p >> 14, n = p & 16383;
        int e = top2i[n * 2 + k];
        int slot = 0;
#pragma unroll 1
        for (int q = 0; q < NEXP; q++) {
            unsigned long long mask = __ballot(e == q);
            int base = __shfl(cnt_reg, q);
            if (e == q) slot = base + __popcll(mask & below);
            if (lane == q) cnt_reg += (int)__popcll(mask);
        }
        if (slot < CAPACITY) {
            list_tok[e * CAPACITY + slot]  = n;
            list_gate[e * CAPACITY + slot] = gates2[n * 2 + k];
        }
    }
}

// ---------------------------------------------------------------------------
// Phase 2.5 (fast path): one-shot We fp32 -> bf16 convert + transpose into the
// exact k-chunk-major layout moe_gemm2 stages with global_load_lds.
// Block b = e*128 + nt*16 + ksi handles a [64k x 128n] tile.
// Output chunk p (16B, p in [0,1024)): kq=p>>7, col=p&127, 8 bf16 =
//   We[e][ksi*64 + kq*8 + j][nt*128 + col],  j = 0..7.
// ---------------------------------------------------------------------------
__global__ __launch_bounds__(256) void convert_we(
    const float* __restrict__ We, unsigned short* __restrict__ WeB)
{
    const int b   = blockIdx.x;
    const int e   = b >> 7;
    const int nt  = (b >> 4) & 7;
    const int ksi = b & 15;
    __shared__ __align__(16) unsigned short T[64][132];   // [k][n] bf16, padded
    const int tid = threadIdx.x;
    const int tc  = (tid & 31) * 4;
    const int tr  = tid >> 5;                             // 0..7
    const float* src = We + ((size_t)e << 20) + (size_t)(ksi * 64) * DIM + nt * 128;
#pragma unroll
    for (int l = 0; l < 8; l++) {
        int dr = l * 8 + tr;
        float4 v = *(const float4*)(src + (size_t)dr * DIM + tc);
        ushort4 u = make_ushort4(f2bf(v.x), f2bf(v.y), f2bf(v.z), f2bf(v.w));
        *(ushort4*)&T[dr][tc] = u;
    }
    __syncthreads();
    unsigned short* dst = WeB + ((size_t)b << 13);        // 8192 shorts per block
#pragma unroll
    for (int i = 0; i < 4; i++) {
        int p = i * 256 + tid;
        int kq = p >> 7, col = p & 127;
        unsigned int w0 = (unsigned int)T[kq * 8 + 0][col] | ((unsigned int)T[kq * 8 + 1][col] << 16);
        unsigned int w1 = (unsigned int)T[kq * 8 + 2][col] | ((unsigned int)T[kq * 8 + 3][col] << 16);
        unsigned int w2 = (unsigned int)T[kq * 8 + 4][col] | ((unsigned int)T[kq * 8 + 5][col] << 16);
        unsigned int w3 = (unsigned int)T[kq * 8 + 6][col] | ((unsigned int)T[kq * 8 + 7][col] << 16);
        *(uint4*)(dst + (size_t)p * 8) = make_uint4(w0, w1, w2, w3);
    }
}

// ---------------------------------------------------------------------------
// Phase 3 (fast path): grouped expert GEMM, m97 structure. 128x128 tile,
// BK=64, both operands bf16 staged via global_load_lds dwordx4 (zero staging
// VALU, zero LDS-write instrs). LDS is k-chunk-major [chunk][row/col][8] so
// ds_read_b128 fragment reads are 2-way-conflict (free) per quarter-wave.
// Epilogue: atomicAdd(out[token], gate*relu(v)).
// ---------------------------------------------------------------------------
__global__ __launch_bounds__(256) void moe_gemm2(
    const unsigned short* __restrict__ xb, const unsigned short* __restrict__ WeB,
    const int* __restrict__ list_tok, const float* __restrict__ list_gate,
    const int* __restrict__ cntc, float* __restrict__ out)
{
    const int bid = blockIdx.x;
    const int e   = bid / 40;
    const int rem = bid % 40;
    const int mt  = rem >> 3;   // 0..4  (5 M-tiles over CAP=640)
    const int nt  = rem & 7;    // 0..7  (8 N-tiles over D=1024)
    const int cnt = cntc[e];
    if (mt * 128 >= cnt) return;
    int valid = cnt - mt * 128; if (valid > 128) valid = 128;

    __shared__ __align__(16) unsigned short As[8 * 128 * 8];  // [chunk][row][8] 16KB
    __shared__ __align__(16) unsigned short Bs[8 * 128 * 8];  // [chunk][col][8] 16KB
    __shared__ int   tok_s[128];
    __shared__ float gate_s[128];

    const int tid = threadIdx.x;
    if (tid < 128) {
        int slot = mt * 128 + tid;
        bool v = tid < valid;
        tok_s[tid]  = v ? list_tok[e * CAPACITY + slot]  : list_tok[e * CAPACITY];
        gate_s[tid] = v ? list_gate[e * CAPACITY + slot] : 0.f;
    }
    __syncthreads();

    // A staging: position p = i*256+tid -> chunk p>>7 (= 2i + tid>>7), row tid&127
    const int arow  = tid & 127;
    const int ahalf = tid >> 7;
    const unsigned short* aG = xb + (size_t)tok_s[arow] * DIM + ahalf * 8;
    // B staging: contiguous pre-arranged chunks
    const unsigned short* bG = WeB + ((size_t)(e * 8 + nt) * 16) * 8192 + (size_t)tid * 8;

    const int wv   = tid >> 6;      // wave id (uniform)
    const int lane = tid & 63;
    const int wm = wv >> 1, wn = wv & 1;
    const int fm = lane & 15, kq = lane >> 4;

    f32x4 acc[4][4];
#pragma unroll
    for (int i = 0; i < 4; i++)
#pragma unroll
        for (int j = 0; j < 4; j++) acc[i][j] = (f32x4){0.f, 0.f, 0.f, 0.f};

    for (int ksi = 0; ksi < 16; ksi++) {
        __syncthreads();            // previous compute done before LDS overwrite
#pragma unroll
        for (int i = 0; i < 4; i++) {
            const int ldsOff = (i * 256 + wv * 64) * 8;   // shorts; +lane*16B by HW
            __builtin_amdgcn_global_load_lds(
                (const __attribute__((address_space(1))) unsigned int*)(aG + ksi * 64 + i * 16),
                (__attribute__((address_space(3))) unsigned int*)(As + ldsOff), 16, 0, 0);
            __builtin_amdgcn_global_load_lds(
                (const __attribute__((address_space(1))) unsigned int*)(bG + (size_t)ksi * 8192 + i * 2048),
                (__attribute__((address_space(3))) unsigned int*)(Bs + ldsOff), 16, 0, 0);
        }
        __syncthreads();            // compiler drains vmcnt(0) before s_barrier
#pragma unroll
        for (int kk = 0; kk < 2; kk++) {
            union { uint4 u; bf16x8 v; } fa[4], fb[4];
#pragma unroll
            for (int i = 0; i < 4; i++)
                fa[i].u = *(const uint4*)(As + ((kk * 4 + kq) * 128 + wm * 64 + i * 16 + fm) * 8);
#pragma unroll
            for (int j = 0; j < 4; j++)
                fb[j].u = *(const uint4*)(Bs + ((kk * 4 + kq) * 128 + wn * 64 + j * 16 + fm) * 8);
#pragma unroll
            for (int i = 0; i < 4; i++)
#pragma unroll
                for (int j = 0; j < 4; j++)
                    acc[i][j] = __builtin_amdgcn_mfma_f32_16x16x32_bf16(
                        fa[i].v, fb[j].v, acc[i][j], 0, 0, 0);
        }
    }

    // ---- epilogue: relu * gate, scatter-add into out[token]
    // C/D layout (m89/m91): col = lane&15, row = (lane>>4)*4 + reg
    const int col0 = nt * 128 + wn * 64 + fm;
#pragma unroll
    for (int i = 0; i < 4; i++) {
        int rbase = wm * 64 + i * 16 + kq * 4;
#pragma unroll
        for (int j = 0; j < 4; j++) {
            int col = col0 + j * 16;
#pragma unroll
            for (int r = 0; r < 4; r++) {
                int row = rbase + r;
                if (row < valid) {
                    float v = acc[i][j][r];
                    v = fmaxf(v, 0.f) * gate_s[row];
                    atomicAdd(out + (size_t)tok_s[row] * DIM + col, v);
                }
            }
        }
    }
}

// ---------------------------------------------------------------------------
// Legacy Phase 3 (fallback if workspace cannot hold WeB): bf16 MFMA with
// in-loop fp32 B staging. Identical to the previously-verified kernel.
// ---------------------------------------------------------------------------
#define MT 128
#define NT 128
#define BK 32
#define LDA 36   // shorts per LDS row: 32 + 4 pad

__global__ __launch_bounds__(256) void moe_gemm(
    const unsigned short* __restrict__ xb, const float* __restrict__ We,
    const int* __restrict__ list_tok, const float* __restrict__ list_gate,
    const int* __restrict__ cntc, float* __restrict__ out)
{
    const int bid = blockIdx.x;
    const int e   = bid / 40;
    const int rem = bid % 40;
    const int mt  = rem >> 3;
    const int nt  = rem & 7;
    const int cnt = cntc[e];
    if (mt * MT >= cnt) return;
    int valid = cnt - mt * MT; if (valid > MT) valid = MT;

    __shared__ unsigned short As[MT * LDA];
    __shared__ unsigned short Bs[NT * LDA];   // B^T: [n][k]
    __shared__ int   tok_s[MT];
    __shared__ float gate_s[MT];

    const int tid = threadIdx.x;
    if (tid < MT) {
        int slot = mt * MT + tid;
        bool v = tid < valid;
        tok_s[tid]  = v ? list_tok[e * CAPACITY + slot]  : list_tok[e * CAPACITY];
        gate_s[tid] = v ? list_gate[e * CAPACITY + slot] : 0.f;
    }
    __syncthreads();

    const int arow = tid >> 1, ah = tid & 1;
    const unsigned short* aptr = xb + (size_t)tok_s[arow] * DIM + ah * 16;
    const int bn0 = (tid & 31) * 4;
    const int bkr = (tid >> 5) * 4;
    const float* bptr = We + (size_t)e * DIM * DIM + (size_t)bkr * DIM + nt * NT + bn0;

    f32x4 acc[4][4];
#pragma unroll
    for (int i = 0; i < 4; i++)
#pragma unroll
        for (int j = 0; j < 4; j++) acc[i][j] = (f32x4){0.f, 0.f, 0.f, 0.f};

    const int lane = tid & 63, wave = tid >> 6;
    const int wm = wave >> 1, wn = wave & 1;
    const int fm = lane & 15, kq = lane >> 4;

    for (int ks = 0; ks < DIM; ks += BK) {
        __syncthreads();
        uint4 a0 = *(const uint4*)(aptr + ks);
        uint4 a1 = *(const uint4*)(aptr + ks + 8);
        {
            unsigned short* d = &As[arow * LDA + ah * 16];
            *(uint2*)(d + 0)  = make_uint2(a0.x, a0.y);
            *(uint2*)(d + 4)  = make_uint2(a0.z, a0.w);
            *(uint2*)(d + 8)  = make_uint2(a1.x, a1.y);
            *(uint2*)(d + 12) = make_uint2(a1.z, a1.w);
        }
        {
            float4 b[4];
#pragma unroll
            for (int j = 0; j < 4; j++)
                b[j] = *(const float4*)(bptr + (size_t)(ks + j) * DIM);
            union { float4 v; float f[4]; } u0, u1, u2, u3;
            u0.v = b[0]; u1.v = b[1]; u2.v = b[2]; u3.v = b[3];
#pragma unroll
            for (int cc = 0; cc < 4; cc++) {
                unsigned int lo = (unsigned int)f2bf(u0.f[cc]) | ((unsigned int)f2bf(u1.f[cc]) << 16);
                unsigned int hi = (unsigned int)f2bf(u2.f[cc]) | ((unsigned int)f2bf(u3.f[cc]) << 16);
                *(uint2*)&Bs[(bn0 + cc) * LDA + bkr] = make_uint2(lo, hi);
            }
        }
        __syncthreads();
        union { uint2 u[2]; bf16x8 v; } fa[4], fb[4];
#pragma unroll
        for (int i = 0; i < 4; i++) {
            const unsigned short* s = &As[(wm * 64 + i * 16 + fm) * LDA + kq * 8];
            fa[i].u[0] = *(const uint2*)(s);
            fa[i].u[1] = *(const uint2*)(s + 4);
        }
#pragma unroll
        for (int j = 0; j < 4; j++) {
            const unsigned short* s = &Bs[(wn * 64 + j * 16 + fm) * LDA + kq * 8];
            fb[j].u[0] = *(const uint2*)(s);
            fb[j].u[1] = *(const uint2*)(s + 4);
        }
#pragma unroll
        for (int i = 0; i < 4; i++)
#pragma unroll
            for (int j = 0; j < 4; j++)
                acc[i][j] = __builtin_amdgcn_mfma_f32_16x16x32_bf16(
                    fa[i].v, fb[j].v, acc[i][j], 0, 0, 0);
    }

    const int col0 = nt * NT + wn * 64 + fm;
#pragma unroll
    for (int i = 0; i < 4; i++) {
        int rbase = wm * 64 + i * 16 + kq * 4;
#pragma unroll
        for (int j = 0; j < 4; j++) {
            int col = col0 + j * 16;
#pragma unroll
            for (int r = 0; r < 4; r++) {
                int row = rbase + r;
                if (row < valid) {
                    float v = acc[i][j][r];
                    v = fmaxf(v, 0.f) * gate_s[row];
                    atomicAdd(out + (size_t)tok_s[row] * DIM + col, v);
                }
            }
        }
    }
}

// ---------------------------------------------------------------------------
extern "C" void kernel_launch(void* const* d_in, const int* in_sizes, int n_in,
                              void* d_out, int out_size, void* d_ws, size_t ws_size,
                              hipStream_t stream)
{
    const float* x  = (const float*)d_in[0];
    const float* Wr = (const float*)d_in[1];
    const float* br = (const float*)d_in[2];
    const float* We = (const float*)d_in[3];
    float* out = (float*)d_out;

    char* ws = (char*)d_ws;
    size_t off = 0;
    unsigned short* xb = (unsigned short*)(ws + off); off += (size_t)N_TOK * DIM * 2;
    int*   top2i     = (int*)(ws + off);   off += (size_t)N_TOK * 2 * 4;
    float* gates2    = (float*)(ws + off); off += (size_t)N_TOK * 2 * 4;
    int*   hist      = (int*)(ws + off);   off += 128 * NEXP * 4;
    int*   pre       = (int*)(ws + off);   off += 128 * NEXP * 4;
    int*   cntc      = (int*)(ws + off);   off += NEXP * 4;
    int*   list_tok  = (int*)(ws + off);   off += NEXP * CAPACITY * 4;
    float* list_gate = (float*)(ws + off); off += NEXP * CAPACITY * 4;
    off = (off + 255) & ~(size_t)255;
    unsigned short* WeB = (unsigned short*)(ws + off);
    size_t need = off + (size_t)NEXP * DIM * DIM * 2;     // +128 MB for bf16 We

    const bool fast = ws_size >= need;

    hipMemsetAsync(out, 0, (size_t)N_TOK * DIM * 4, stream);
    if (fast)
        convert_we<<<NEXP * 8 * 16, 256, 0, stream>>>(We, WeB);
    router_kernel<<<N_TOK / 64, 256, 0, stream>>>(x, Wr, br, xb, top2i, gates2);
    hist_kernel<<<128, 256, 0, stream>>>(top2i, hist);
    scan_kernel<<<1, 64, 0, stream>>>(hist, pre, cntc);
    rank_kernel<<<128, 64, 0, stream>>>(top2i, gates2, pre, list_tok, list_gate);
    if (fast)
        moe_gemm2<<<NEXP * 40, 256, 0, stream>>>(xb, WeB, list_tok, list_gate, cntc, out);
    else
        moe_gemm<<<NEXP * 40, 256, 0, stream>>>(xb, We, list_tok, list_gate, cntc, out);
}

// Round 3
// 680.269 us; speedup vs baseline: 1.0931x; 1.0931x over previous
//
#include <hip/hip_runtime.h>
#include <hip/hip_bf16.h>
#include <cstdint>
#include <cstddef>

#define N_TOK 16384
#define DIM   1024
#define NEXP  64
#define CAPACITY 640

typedef __bf16 bf16x8 __attribute__((ext_vector_type(8)));
typedef float  f32x4  __attribute__((ext_vector_type(4)));

__device__ __forceinline__ unsigned short f2bf(float f) {
    union { float f; unsigned int u; } a; a.f = f;
    unsigned int r = a.u + 0x7FFFu + ((a.u >> 16) & 1u);  // RTNE
    return (unsigned short)(r >> 16);
}

// ---------------------------------------------------------------------------
// Phase 1 (single dispatch, 3 independent block roles):
//   blocks [0,256):     router GEMM + top-2 + gates + x->bf16 + hist atomics
//   blocks [256,8448):  We fp32 -> bf16 convert into k-chunk-major WeB layout
//                       (8192 blocks: b = e*128 + nt*16 + ksi, e in [0,64))
//   blocks [8448,8960): zero the output buffer (replaces hipMemsetAsync(out))
// Fallback path launches with grid=256 (router role only).
// ---------------------------------------------------------------------------
__global__ __launch_bounds__(256) void router_convert(
    const float* __restrict__ x, const float* __restrict__ Wr,
    const float* __restrict__ br, const float* __restrict__ We,
    unsigned short* __restrict__ xb, unsigned short* __restrict__ WeB,
    int* __restrict__ top2i, float* __restrict__ gates2,
    int* __restrict__ hist, float* __restrict__ out)
{
    __shared__ __align__(16) float smem[2][64][68];   // 34816 B (router tiles)
    const int tid = threadIdx.x;

    if (blockIdx.x >= 8448) {
        // ---- role 3: zero out[] (64 MB / 512 blocks = 128 KB each)
        const int z = blockIdx.x - 8448;
        float4* o = (float4*)(out + (size_t)z * 32768);
        const float4 zero = make_float4(0.f, 0.f, 0.f, 0.f);
#pragma unroll
        for (int l = 0; l < 32; l++) o[l * 256 + tid] = zero;
        return;
    }

    if (blockIdx.x >= 256) {
        // ---- role 2: We convert+transpose. Block b = e*128 + nt*16 + ksi.
        // Output chunk p in [0,1024): kq=p>>7, col=p&127 -> 8 bf16 rows.
        const int b   = blockIdx.x - 256;
        const int e   = b >> 7;
        const int nt  = (b >> 4) & 7;
        const int ksi = b & 15;
        unsigned short (*T)[132] = (unsigned short (*)[132])smem;  // 16896 B alias
        const int tc  = (tid & 31) * 4;
        const int tr  = tid >> 5;
        const float* src = We + ((size_t)e << 20) + (size_t)(ksi * 64) * DIM + nt * 128;
#pragma unroll
        for (int l = 0; l < 8; l++) {
            int dr = l * 8 + tr;
            float4 v = *(const float4*)(src + (size_t)dr * DIM + tc);
            ushort4 u = make_ushort4(f2bf(v.x), f2bf(v.y), f2bf(v.z), f2bf(v.w));
            *(ushort4*)&T[dr][tc] = u;
        }
        __syncthreads();
        unsigned short* dst = WeB + ((size_t)b << 13);   // 8192 shorts per block
#pragma unroll
        for (int i = 0; i < 4; i++) {
            int p = i * 256 + tid;
            int kq = p >> 7, col = p & 127;
            unsigned int w0 = (unsigned int)T[kq * 8 + 0][col] | ((unsigned int)T[kq * 8 + 1][col] << 16);
            unsigned int w1 = (unsigned int)T[kq * 8 + 2][col] | ((unsigned int)T[kq * 8 + 3][col] << 16);
            unsigned int w2 = (unsigned int)T[kq * 8 + 4][col] | ((unsigned int)T[kq * 8 + 5][col] << 16);
            unsigned int w3 = (unsigned int)T[kq * 8 + 6][col] | ((unsigned int)T[kq * 8 + 7][col] << 16);
            *(uint4*)(dst + (size_t)p * 8) = make_uint4(w0, w1, w2, w3);
        }
        return;
    }

    // ---- role 1: router. Block handles 64 tokens x 64 experts, K-tiled by 64.
    float (*xs)[68] = smem[0];
    float (*wT)[68] = smem[1];
    const int t0  = blockIdx.x * 64;
    const int tm  = tid >> 4;     // 0..15 token group
    const int te  = tid & 15;     // 0..15 expert group

    float acc[4][4];
#pragma unroll
    for (int i = 0; i < 4; i++)
#pragma unroll
        for (int j = 0; j < 4; j++) acc[i][j] = 0.f;

    for (int ks = 0; ks < DIM; ks += 64) {
        __syncthreads();
#pragma unroll
        for (int l = 0; l < 4; l++) {
            int row = l * 16 + tm;
            int col = te * 4;
            float4 v = *(const float4*)(x + (size_t)(t0 + row) * DIM + ks + col);
            *(float4*)&xs[row][col] = v;
            ushort4 b = make_ushort4(f2bf(v.x), f2bf(v.y), f2bf(v.z), f2bf(v.w));
            *(ushort4*)(xb + (size_t)(t0 + row) * DIM + ks + col) = b;
        }
#pragma unroll
        for (int l = 0; l < 4; l++) {
            int kr = l * 16 + tm;
            int ec = te * 4;
            float4 v = *(const float4*)(Wr + (size_t)(ks + kr) * NEXP + ec);
            wT[ec + 0][kr] = v.x; wT[ec + 1][kr] = v.y;
            wT[ec + 2][kr] = v.z; wT[ec + 3][kr] = v.w;
        }
        __syncthreads();
#pragma unroll 4
        for (int kk = 0; kk < 64; kk += 4) {
            float4 xv[4], wv[4];
#pragma unroll
            for (int i = 0; i < 4; i++) xv[i] = *(float4*)&xs[tm + i * 16][kk];
#pragma unroll
            for (int j = 0; j < 4; j++) wv[j] = *(float4*)&wT[te + j * 16][kk];
#pragma unroll
            for (int i = 0; i < 4; i++)
#pragma unroll
                for (int j = 0; j < 4; j++)
                    acc[i][j] += xv[i].x * wv[j].x + xv[i].y * wv[j].y +
                                 xv[i].z * wv[j].z + xv[i].w * wv[j].w;
        }
    }
    __syncthreads();
#pragma unroll
    for (int i = 0; i < 4; i++)
#pragma unroll
        for (int j = 0; j < 4; j++)
            xs[tm + i * 16][te + j * 16] = acc[i][j] + br[te + j * 16];
    __syncthreads();
    if (tid < 64) {
        int n = t0 + tid;
        float v1 = -1e30f, v2 = -1e30f; int i1 = 0, i2 = 0;
        for (int e = 0; e < 64; e++) {
            float v = xs[tid][e];
            if (v > v1)      { v2 = v1; i2 = i1; v1 = v; i1 = e; }
            else if (v > v2) { v2 = v;  i2 = e; }
        }
        float g0 = 1.f / (1.f + expf(v2 - v1));   // softmax over (v1,v2), v1>=v2
        top2i[n * 2 + 0] = i1; top2i[n * 2 + 1] = i2;
        gates2[n * 2 + 0] = g0; gates2[n * 2 + 1] = 1.f - g0;
        // hist: position p = k*N + n, chunk = p>>8 = k*64 + (n>>8)
        atomicAdd(&hist[(n >> 8) * NEXP + i1], 1);
        atomicAdd(&hist[(64 + (n >> 8)) * NEXP + i2], 1);
    }
}

// ---------------------------------------------------------------------------
// Phase 2: stable intra-chunk ranks via wave ballot. Each block computes its
// own per-expert prefix from hist (scan fused in); block 127 emits cntc.
// ---------------------------------------------------------------------------
__global__ __launch_bounds__(64) void rank_kernel(
    const int* __restrict__ top2i, const float* __restrict__ gates2,
    const int* __restrict__ hist, int* __restrict__ list_tok,
    float* __restrict__ list_gate, int* __restrict__ cntc)
{
    int lane = threadIdx.x;
    int c = blockIdx.x;
    int cnt_reg = 0;                               // lane e owns expert e's counter
#pragma unroll 4
    for (int cc = 0; cc < c; cc++) cnt_reg += hist[cc * NEXP + lane];
    unsigned long long below = (1ull << lane) - 1ull;
    for (int r = 0; r < 4; r++) {                  // 4 x 64 = 256 positions, in order
        int p = c * 256 + r * 64 + lane;
        int k = p >> 14, n = p & 16383;
        int e = top2i[n * 2 + k];
        int slot = 0;
#pragma unroll 1
        for (int q = 0; q < NEXP; q++) {
            unsigned long long mask = __ballot(e == q);
            int base = __shfl(cnt_reg, q);
            if (e == q) slot = base + __popcll(mask & below);
            if (lane == q) cnt_reg += (int)__popcll(mask);
        }
        if (slot < CAPACITY) {
            list_tok[e * CAPACITY + slot]  = n;
            list_gate[e * CAPACITY + slot] = gates2[n * 2 + k];
        }
    }
    if (c == 127) cntc[lane] = cnt_reg < CAPACITY ? cnt_reg : CAPACITY;
}

// ---------------------------------------------------------------------------
// Phase 3 (fast path): grouped expert GEMM, 128x128 tile, BK=64, bf16 MFMA.
// 2-phase double-buffered pipeline (T3-minimum): issue next tile's
// global_load_lds, compute current tile, ONE barrier (vmcnt(0) drain lands
// after the MFMAs, so the gathered-A latency hides under compute).
// ---------------------------------------------------------------------------
__global__ __launch_bounds__(256) void moe_gemm3(
    const unsigned short* __restrict__ xb, const unsigned short* __restrict__ WeB,
    const int* __restrict__ list_tok, const float* __restrict__ list_gate,
    const int* __restrict__ cntc, float* __restrict__ out)
{
    const int bid = blockIdx.x;
    const int e   = bid / 40;
    const int rem = bid % 40;
    const int mt  = rem >> 3;   // 0..4  (5 M-tiles over CAP=640)
    const int nt  = rem & 7;    // 0..7  (8 N-tiles over D=1024)
    const int cnt = cntc[e];
    if (mt * 128 >= cnt) return;
    int valid = cnt - mt * 128; if (valid > 128) valid = 128;

    __shared__ __align__(16) unsigned short As[2][8192];  // [buf][chunk][row][8] 2x16KB
    __shared__ __align__(16) unsigned short Bs[2][8192];  // [buf][chunk][col][8] 2x16KB
    __shared__ int   tok_s[128];
    __shared__ float gate_s[128];

    const int tid = threadIdx.x;
    if (tid < 128) {
        int slot = mt * 128 + tid;
        bool v = tid < valid;
        tok_s[tid]  = v ? list_tok[e * CAPACITY + slot]  : list_tok[e * CAPACITY];
        gate_s[tid] = v ? list_gate[e * CAPACITY + slot] : 0.f;
    }
    __syncthreads();

    // A staging: position p = i*256+tid -> chunk p>>7, row tid&127, half tid>>7
    const int arow  = tid & 127;
    const int ahalf = tid >> 7;
    const unsigned short* aG = xb + (size_t)tok_s[arow] * DIM + ahalf * 8;
    const unsigned short* bG = WeB + ((size_t)(e * 8 + nt) * 16) * 8192 + (size_t)tid * 8;

    const int wv   = tid >> 6;
    const int lane = tid & 63;
    const int wm = wv >> 1, wn = wv & 1;
    const int fm = lane & 15, kq = lane >> 4;

    f32x4 acc[4][4];
#pragma unroll
    for (int i = 0; i < 4; i++)
#pragma unroll
        for (int j = 0; j < 4; j++) acc[i][j] = (f32x4){0.f, 0.f, 0.f, 0.f};

    auto stage = [&](int buf, int ksi) {
#pragma unroll
        for (int i = 0; i < 4; i++) {
            const int ldsOff = (i * 256 + wv * 64) * 8;   // shorts; +lane*16B by HW
            __builtin_amdgcn_global_load_lds(
                (const __attribute__((address_space(1))) unsigned int*)(aG + ksi * 64 + i * 16),
                (__attribute__((address_space(3))) unsigned int*)(&As[buf][ldsOff]), 16, 0, 0);
            __builtin_amdgcn_global_load_lds(
                (const __attribute__((address_space(1))) unsigned int*)(bG + (size_t)ksi * 8192 + i * 2048),
                (__attribute__((address_space(3))) unsigned int*)(&Bs[buf][ldsOff]), 16, 0, 0);
        }
    };
    auto compute = [&](int buf) {
#pragma unroll
        for (int kk = 0; kk < 2; kk++) {
            union { uint4 u; bf16x8 v; } fa[4], fb[4];
#pragma unroll
            for (int i = 0; i < 4; i++)
                fa[i].u = *(const uint4*)(&As[buf][((kk * 4 + kq) * 128 + wm * 64 + i * 16 + fm) * 8]);
#pragma unroll
            for (int j = 0; j < 4; j++)
                fb[j].u = *(const uint4*)(&Bs[buf][((kk * 4 + kq) * 128 + wn * 64 + j * 16 + fm) * 8]);
#pragma unroll
            for (int i = 0; i < 4; i++)
#pragma unroll
                for (int j = 0; j < 4; j++)
                    acc[i][j] = __builtin_amdgcn_mfma_f32_16x16x32_bf16(
                        fa[i].v, fb[j].v, acc[i][j], 0, 0, 0);
        }
    };

    stage(0, 0);
    __syncthreads();          // drain tile-0 loads
    int cur = 0;
#pragma unroll 1
    for (int ksi = 1; ksi < 16; ksi++) {
        stage(cur ^ 1, ksi);  // issue next tile (other buffer) BEFORE compute
        compute(cur);
        __syncthreads();      // single per-iter drain: vmcnt(0)+barrier after MFMAs
        cur ^= 1;
    }
    compute(cur);             // last tile, no prefetch

    // ---- epilogue: relu * gate, scatter-add into out[token]
    // C/D layout (m89/m91): col = lane&15, row = (lane>>4)*4 + reg
    const int col0 = nt * 128 + wn * 64 + fm;
#pragma unroll
    for (int i = 0; i < 4; i++) {
        int rbase = wm * 64 + i * 16 + kq * 4;
#pragma unroll
        for (int j = 0; j < 4; j++) {
            int col = col0 + j * 16;
#pragma unroll
            for (int r = 0; r < 4; r++) {
                int row = rbase + r;
                if (row < valid) {
                    float v = acc[i][j][r];
                    v = fmaxf(v, 0.f) * gate_s[row];
                    atomicAdd(out + (size_t)tok_s[row] * DIM + col, v);
                }
            }
        }
    }
}

// ---------------------------------------------------------------------------
// Legacy Phase 3 (fallback if workspace cannot hold WeB): bf16 MFMA with
// in-loop fp32 B staging.
// ---------------------------------------------------------------------------
#define MT 128
#define NT 128
#define BK 32
#define LDA 36   // shorts per LDS row: 32 + 4 pad

__global__ __launch_bounds__(256) void moe_gemm(
    const unsigned short* __restrict__ xb, const float* __restrict__ We,
    const int* __restrict__ list_tok, const float* __restrict__ list_gate,
    const int* __restrict__ cntc, float* __restrict__ out)
{
    const int bid = blockIdx.x;
    const int e   = bid / 40;
    const int rem = bid % 40;
    const int mt  = rem >> 3;
    const int nt  = rem & 7;
    const int cnt = cntc[e];
    if (mt * MT >= cnt) return;
    int valid = cnt - mt * MT; if (valid > MT) valid = MT;

    __shared__ unsigned short As[MT * LDA];
    __shared__ unsigned short Bs[NT * LDA];   // B^T: [n][k]
    __shared__ int   tok_s[MT];
    __shared__ float gate_s[MT];

    const int tid = threadIdx.x;
    if (tid < MT) {
        int slot = mt * MT + tid;
        bool v = tid < valid;
        tok_s[tid]  = v ? list_tok[e * CAPACITY + slot]  : list_tok[e * CAPACITY];
        gate_s[tid] = v ? list_gate[e * CAPACITY + slot] : 0.f;
    }
    __syncthreads();

    const int arow = tid >> 1, ah = tid & 1;
    const unsigned short* aptr = xb + (size_t)tok_s[arow] * DIM + ah * 16;
    const int bn0 = (tid & 31) * 4;
    const int bkr = (tid >> 5) * 4;
    const float* bptr = We + (size_t)e * DIM * DIM + (size_t)bkr * DIM + nt * NT + bn0;

    f32x4 acc[4][4];
#pragma unroll
    for (int i = 0; i < 4; i++)
#pragma unroll
        for (int j = 0; j < 4; j++) acc[i][j] = (f32x4){0.f, 0.f, 0.f, 0.f};

    const int lane = tid & 63, wave = tid >> 6;
    const int wm = wave >> 1, wn = wave & 1;
    const int fm = lane & 15, kq = lane >> 4;

    for (int ks = 0; ks < DIM; ks += BK) {
        __syncthreads();
        uint4 a0 = *(const uint4*)(aptr + ks);
        uint4 a1 = *(const uint4*)(aptr + ks + 8);
        {
            unsigned short* d = &As[arow * LDA + ah * 16];
            *(uint2*)(d + 0)  = make_uint2(a0.x, a0.y);
            *(uint2*)(d + 4)  = make_uint2(a0.z, a0.w);
            *(uint2*)(d + 8)  = make_uint2(a1.x, a1.y);
            *(uint2*)(d + 12) = make_uint2(a1.z, a1.w);
        }
        {
            float4 b[4];
#pragma unroll
            for (int j = 0; j < 4; j++)
                b[j] = *(const float4*)(bptr + (size_t)(ks + j) * DIM);
            union { float4 v; float f[4]; } u0, u1, u2, u3;
            u0.v = b[0]; u1.v = b[1]; u2.v = b[2]; u3.v = b[3];
#pragma unroll
            for (int cc = 0; cc < 4; cc++) {
                unsigned int lo = (unsigned int)f2bf(u0.f[cc]) | ((unsigned int)f2bf(u1.f[cc]) << 16);
                unsigned int hi = (unsigned int)f2bf(u2.f[cc]) | ((unsigned int)f2bf(u3.f[cc]) << 16);
                *(uint2*)&Bs[(bn0 + cc) * LDA + bkr] = make_uint2(lo, hi);
            }
        }
        __syncthreads();
        union { uint2 u[2]; bf16x8 v; } fa[4], fb[4];
#pragma unroll
        for (int i = 0; i < 4; i++) {
            const unsigned short* s = &As[(wm * 64 + i * 16 + fm) * LDA + kq * 8];
            fa[i].u[0] = *(const uint2*)(s);
            fa[i].u[1] = *(const uint2*)(s + 4);
        }
#pragma unroll
        for (int j = 0; j < 4; j++) {
            const unsigned short* s = &Bs[(wn * 64 + j * 16 + fm) * LDA + kq * 8];
            fb[j].u[0] = *(const uint2*)(s);
            fb[j].u[1] = *(const uint2*)(s + 4);
        }
#pragma unroll
        for (int i = 0; i < 4; i++)
#pragma unroll
            for (int j = 0; j < 4; j++)
                acc[i][j] = __builtin_amdgcn_mfma_f32_16x16x32_bf16(
                    fa[i].v, fb[j].v, acc[i][j], 0, 0, 0);
    }

    const int col0 = nt * NT + wn * 64 + fm;
#pragma unroll
    for (int i = 0; i < 4; i++) {
        int rbase = wm * 64 + i * 16 + kq * 4;
#pragma unroll
        for (int j = 0; j < 4; j++) {
            int col = col0 + j * 16;
#pragma unroll
            for (int r = 0; r < 4; r++) {
                int row = rbase + r;
                if (row < valid) {
                    float v = acc[i][j][r];
                    v = fmaxf(v, 0.f) * gate_s[row];
                    atomicAdd(out + (size_t)tok_s[row] * DIM + col, v);
                }
            }
        }
    }
}

// ---------------------------------------------------------------------------
extern "C" void kernel_launch(void* const* d_in, const int* in_sizes, int n_in,
                              void* d_out, int out_size, void* d_ws, size_t ws_size,
                              hipStream_t stream)
{
    const float* x  = (const float*)d_in[0];
    const float* Wr = (const float*)d_in[1];
    const float* br = (const float*)d_in[2];
    const float* We = (const float*)d_in[3];
    float* out = (float*)d_out;

    char* ws = (char*)d_ws;
    size_t off = 0;
    unsigned short* xb = (unsigned short*)(ws + off); off += (size_t)N_TOK * DIM * 2;
    int*   top2i     = (int*)(ws + off);   off += (size_t)N_TOK * 2 * 4;
    float* gates2    = (float*)(ws + off); off += (size_t)N_TOK * 2 * 4;
    int*   hist      = (int*)(ws + off);   off += 128 * NEXP * 4;
    int*   cntc      = (int*)(ws + off);   off += NEXP * 4;
    int*   list_tok  = (int*)(ws + off);   off += NEXP * CAPACITY * 4;
    float* list_gate = (float*)(ws + off); off += NEXP * CAPACITY * 4;
    off = (off + 255) & ~(size_t)255;
    unsigned short* WeB = (unsigned short*)(ws + off);
    size_t need = off + (size_t)NEXP * DIM * DIM * 2;     // +128 MB for bf16 We

    const bool fast = ws_size >= need;

    hipMemsetAsync(hist, 0, 128 * NEXP * 4, stream);
    if (fast) {
        // one dispatch: router (256) + We-convert (8192) + out-zero (512)
        router_convert<<<8960, 256, 0, stream>>>(x, Wr, br, We, xb, WeB,
                                                 top2i, gates2, hist, out);
        rank_kernel<<<128, 64, 0, stream>>>(top2i, gates2, hist,
                                            list_tok, list_gate, cntc);
        moe_gemm3<<<NEXP * 40, 256, 0, stream>>>(xb, WeB, list_tok, list_gate,
                                                 cntc, out);
    } else {
        hipMemsetAsync(out, 0, (size_t)N_TOK * DIM * 4, stream);
        router_convert<<<256, 256, 0, stream>>>(x, Wr, br, We, xb, xb,
                                                top2i, gates2, hist, out);
        rank_kernel<<<128, 64, 0, stream>>>(top2i, gates2, hist,
                                            list_tok, list_gate, cntc);
        moe_gemm<<<NEXP * 40, 256, 0, stream>>>(xb, We, list_tok, list_gate,
                                                cntc, out);
    }
}

// Round 4
// 678.149 us; speedup vs baseline: 1.0965x; 1.0031x over previous
//
#include <hip/hip_runtime.h>
#include <hip/hip_bf16.h>
#include <cstdint>
#include <cstddef>

#define N_TOK 16384
#define DIM   1024
#define NEXP  64
#define CAPACITY 640

typedef __bf16 bf16x8 __attribute__((ext_vector_type(8)));
typedef float  f32x4  __attribute__((ext_vector_type(4)));

__device__ __forceinline__ unsigned short f2bf(float f) {
    union { float f; unsigned int u; } a; a.f = f;
    unsigned int r = a.u + 0x7FFFu + ((a.u >> 16) & 1u);  // RTNE
    return (unsigned short)(r >> 16);
}

// ---------------------------------------------------------------------------
// Phase 1 (single dispatch, block roles):
//   blocks [0,256):     router GEMM + top-2 + gates + x->bf16 + hist atomics
//   blocks [256,8448):  We fp32 -> bf16 convert into k-chunk-major WeB layout
//   blocks [8448,8960): zero out[] (ONLY launched on the atomic fallback path)
// ---------------------------------------------------------------------------
__global__ __launch_bounds__(256) void router_convert(
    const float* __restrict__ x, const float* __restrict__ Wr,
    const float* __restrict__ br, const float* __restrict__ We,
    unsigned short* __restrict__ xb, unsigned short* __restrict__ WeB,
    int* __restrict__ top2i, float* __restrict__ gates2,
    int* __restrict__ hist, float* __restrict__ out)
{
    __shared__ __align__(16) float smem[2][64][68];   // 34816 B (router tiles)
    const int tid = threadIdx.x;

    if (blockIdx.x >= 8448) {
        // ---- role 3 (fallback only): zero out[] (64 MB / 512 blocks)
        const int z = blockIdx.x - 8448;
        float4* o = (float4*)(out + (size_t)z * 32768);
        const float4 zero = make_float4(0.f, 0.f, 0.f, 0.f);
#pragma unroll
        for (int l = 0; l < 32; l++) o[l * 256 + tid] = zero;
        return;
    }

    if (blockIdx.x >= 256) {
        // ---- role 2: We convert+transpose. Block b = e*128 + nt*16 + ksi.
        const int b   = blockIdx.x - 256;
        const int e   = b >> 7;
        const int nt  = (b >> 4) & 7;
        const int ksi = b & 15;
        unsigned short (*T)[132] = (unsigned short (*)[132])smem;  // alias
        const int tc  = (tid & 31) * 4;
        const int tr  = tid >> 5;
        const float* src = We + ((size_t)e << 20) + (size_t)(ksi * 64) * DIM + nt * 128;
#pragma unroll
        for (int l = 0; l < 8; l++) {
            int dr = l * 8 + tr;
            float4 v = *(const float4*)(src + (size_t)dr * DIM + tc);
            ushort4 u = make_ushort4(f2bf(v.x), f2bf(v.y), f2bf(v.z), f2bf(v.w));
            *(ushort4*)&T[dr][tc] = u;
        }
        __syncthreads();
        unsigned short* dst = WeB + ((size_t)b << 13);   // 8192 shorts per block
#pragma unroll
        for (int i = 0; i < 4; i++) {
            int p = i * 256 + tid;
            int kq = p >> 7, col = p & 127;
            unsigned int w0 = (unsigned int)T[kq * 8 + 0][col] | ((unsigned int)T[kq * 8 + 1][col] << 16);
            unsigned int w1 = (unsigned int)T[kq * 8 + 2][col] | ((unsigned int)T[kq * 8 + 3][col] << 16);
            unsigned int w2 = (unsigned int)T[kq * 8 + 4][col] | ((unsigned int)T[kq * 8 + 5][col] << 16);
            unsigned int w3 = (unsigned int)T[kq * 8 + 6][col] | ((unsigned int)T[kq * 8 + 7][col] << 16);
            *(uint4*)(dst + (size_t)p * 8) = make_uint4(w0, w1, w2, w3);
        }
        return;
    }

    // ---- role 1: router. Block handles 64 tokens x 64 experts, K-tiled by 64.
    float (*xs)[68] = smem[0];
    float (*wT)[68] = smem[1];
    const int t0  = blockIdx.x * 64;
    const int tm  = tid >> 4;
    const int te  = tid & 15;

    float acc[4][4];
#pragma unroll
    for (int i = 0; i < 4; i++)
#pragma unroll
        for (int j = 0; j < 4; j++) acc[i][j] = 0.f;

    for (int ks = 0; ks < DIM; ks += 64) {
        __syncthreads();
#pragma unroll
        for (int l = 0; l < 4; l++) {
            int row = l * 16 + tm;
            int col = te * 4;
            float4 v = *(const float4*)(x + (size_t)(t0 + row) * DIM + ks + col);
            *(float4*)&xs[row][col] = v;
            ushort4 b = make_ushort4(f2bf(v.x), f2bf(v.y), f2bf(v.z), f2bf(v.w));
            *(ushort4*)(xb + (size_t)(t0 + row) * DIM + ks + col) = b;
        }
#pragma unroll
        for (int l = 0; l < 4; l++) {
            int kr = l * 16 + tm;
            int ec = te * 4;
            float4 v = *(const float4*)(Wr + (size_t)(ks + kr) * NEXP + ec);
            wT[ec + 0][kr] = v.x; wT[ec + 1][kr] = v.y;
            wT[ec + 2][kr] = v.z; wT[ec + 3][kr] = v.w;
        }
        __syncthreads();
#pragma unroll 4
        for (int kk = 0; kk < 64; kk += 4) {
            float4 xv[4], wv[4];
#pragma unroll
            for (int i = 0; i < 4; i++) xv[i] = *(float4*)&xs[tm + i * 16][kk];
#pragma unroll
            for (int j = 0; j < 4; j++) wv[j] = *(float4*)&wT[te + j * 16][kk];
#pragma unroll
            for (int i = 0; i < 4; i++)
#pragma unroll
                for (int j = 0; j < 4; j++)
                    acc[i][j] += xv[i].x * wv[j].x + xv[i].y * wv[j].y +
                                 xv[i].z * wv[j].z + xv[i].w * wv[j].w;
        }
    }
    __syncthreads();
#pragma unroll
    for (int i = 0; i < 4; i++)
#pragma unroll
        for (int j = 0; j < 4; j++)
            xs[tm + i * 16][te + j * 16] = acc[i][j] + br[te + j * 16];
    __syncthreads();
    if (tid < 64) {
        int n = t0 + tid;
        float v1 = -1e30f, v2 = -1e30f; int i1 = 0, i2 = 0;
        for (int e = 0; e < 64; e++) {
            float v = xs[tid][e];
            if (v > v1)      { v2 = v1; i2 = i1; v1 = v; i1 = e; }
            else if (v > v2) { v2 = v;  i2 = e; }
        }
        float g0 = 1.f / (1.f + expf(v2 - v1));   // softmax over (v1,v2), v1>=v2
        top2i[n * 2 + 0] = i1; top2i[n * 2 + 1] = i2;
        gates2[n * 2 + 0] = g0; gates2[n * 2 + 1] = 1.f - g0;
        // hist: position p = k*N + n, chunk = p>>8 = k*64 + (n>>8)
        atomicAdd(&hist[(n >> 8) * NEXP + i1], 1);
        atomicAdd(&hist[(64 + (n >> 8)) * NEXP + i2], 1);
    }
}

// ---------------------------------------------------------------------------
// Phase 2: stable intra-chunk ranks via wave ballot (scan fused in).
// Writes list_tok with k encoded in bit 16, and slot_of[p] for every p=k*N+n
// (used by combine_kernel to gate dropped tokens). Block 127 emits cntc.
// ---------------------------------------------------------------------------
__global__ __launch_bounds__(64) void rank_kernel(
    const int* __restrict__ top2i, const float* __restrict__ gates2,
    const int* __restrict__ hist, int* __restrict__ list_tok,
    float* __restrict__ list_gate, int* __restrict__ cntc,
    int* __restrict__ slot_of)
{
    int lane = threadIdx.x;
    int c = blockIdx.x;
    int cnt_reg = 0;                               // lane e owns expert e's counter
#pragma unroll 4
    for (int cc = 0; cc < c; cc++) cnt_reg += hist[cc * NEXP + lane];
    unsigned long long below = (1ull << lane) - 1ull;
    for (int r = 0; r < 4; r++) {                  // 4 x 64 = 256 positions, in order
        int p = c * 256 + r * 64 + lane;
        int k = p >> 14, n = p & 16383;
        int e = top2i[n * 2 + k];
        int slot = 0;
#pragma unroll 1
        for (int q = 0; q < NEXP; q++) {
            unsigned long long mask = __ballot(e == q);
            int base = __shfl(cnt_reg, q);
            if (e == q) slot = base + __popcll(mask & below);
            if (lane == q) cnt_reg += (int)__popcll(mask);
        }
        slot_of[p] = slot;                         // >= CAPACITY means dropped
        if (slot < CAPACITY) {
            list_tok[e * CAPACITY + slot]  = n | (k << 16);
            list_gate[e * CAPACITY + slot] = gates2[n * 2 + k];
        }
    }
    if (c == 127) cntc[lane] = cnt_reg < CAPACITY ? cnt_reg : CAPACITY;
}

// ---------------------------------------------------------------------------
// Phase 3: grouped expert GEMM, 128x128 tile, BK=64, bf16 MFMA, 2-phase
// double-buffered global_load_lds pipeline.
// MODE 0: epilogue atomicAdd into out[token] (fallback).
// MODE 1: epilogue plain f32 store into comb[k*N + n][col] (each cell is
//         written exactly once; no atomics, no zero-init needed).
// ---------------------------------------------------------------------------
template <int MODE>
__global__ __launch_bounds__(256) void moe_gemm3t(
    const unsigned short* __restrict__ xb, const unsigned short* __restrict__ WeB,
    const int* __restrict__ list_tok, const float* __restrict__ list_gate,
    const int* __restrict__ cntc, float* __restrict__ outc)
{
    const int bid = blockIdx.x;
    const int e   = bid / 40;
    const int rem = bid % 40;
    const int mt  = rem >> 3;   // 0..4  (5 M-tiles over CAP=640)
    const int nt  = rem & 7;    // 0..7  (8 N-tiles over D=1024)
    const int cnt = cntc[e];
    if (mt * 128 >= cnt) return;
    int valid = cnt - mt * 128; if (valid > 128) valid = 128;

    __shared__ __align__(16) unsigned short As[2][8192];  // [buf][chunk][row][8]
    __shared__ __align__(16) unsigned short Bs[2][8192];  // [buf][chunk][col][8]
    __shared__ int   tok_s[128];
    __shared__ int   crow_s[128];
    __shared__ float gate_s[128];

    const int tid = threadIdx.x;
    if (tid < 128) {
        int slot = mt * 128 + tid;
        bool v = tid < valid;
        int raw = v ? list_tok[e * CAPACITY + slot] : list_tok[e * CAPACITY];
        int n   = raw & 0x3FFF;
        tok_s[tid]  = n;
        crow_s[tid] = ((raw >> 16) << 14) | n;    // comb row = k*N + n
        gate_s[tid] = v ? list_gate[e * CAPACITY + slot] : 0.f;
    }
    __syncthreads();

    // A staging: position p = i*256+tid -> chunk p>>7, row tid&127, half tid>>7
    const int arow  = tid & 127;
    const int ahalf = tid >> 7;
    const unsigned short* aG = xb + (size_t)tok_s[arow] * DIM + ahalf * 8;
    const unsigned short* bG = WeB + ((size_t)(e * 8 + nt) * 16) * 8192 + (size_t)tid * 8;

    const int wv   = tid >> 6;
    const int lane = tid & 63;
    const int wm = wv >> 1, wn = wv & 1;
    const int fm = lane & 15, kq = lane >> 4;

    f32x4 acc[4][4];
#pragma unroll
    for (int i = 0; i < 4; i++)
#pragma unroll
        for (int j = 0; j < 4; j++) acc[i][j] = (f32x4){0.f, 0.f, 0.f, 0.f};

    auto stage = [&](int buf, int ksi) {
#pragma unroll
        for (int i = 0; i < 4; i++) {
            const int ldsOff = (i * 256 + wv * 64) * 8;   // shorts; +lane*16B by HW
            __builtin_amdgcn_global_load_lds(
                (const __attribute__((address_space(1))) unsigned int*)(aG + ksi * 64 + i * 16),
                (__attribute__((address_space(3))) unsigned int*)(&As[buf][ldsOff]), 16, 0, 0);
            __builtin_amdgcn_global_load_lds(
                (const __attribute__((address_space(1))) unsigned int*)(bG + (size_t)ksi * 8192 + i * 2048),
                (__attribute__((address_space(3))) unsigned int*)(&Bs[buf][ldsOff]), 16, 0, 0);
        }
    };
    auto compute = [&](int buf) {
#pragma unroll
        for (int kk = 0; kk < 2; kk++) {
            union { uint4 u; bf16x8 v; } fa[4], fb[4];
#pragma unroll
            for (int i = 0; i < 4; i++)
                fa[i].u = *(const uint4*)(&As[buf][((kk * 4 + kq) * 128 + wm * 64 + i * 16 + fm) * 8]);
#pragma unroll
            for (int j = 0; j < 4; j++)
                fb[j].u = *(const uint4*)(&Bs[buf][((kk * 4 + kq) * 128 + wn * 64 + j * 16 + fm) * 8]);
#pragma unroll
            for (int i = 0; i < 4; i++)
#pragma unroll
                for (int j = 0; j < 4; j++)
                    acc[i][j] = __builtin_amdgcn_mfma_f32_16x16x32_bf16(
                        fa[i].v, fb[j].v, acc[i][j], 0, 0, 0);
        }
    };

    stage(0, 0);
    __syncthreads();          // drain tile-0 loads
    int cur = 0;
#pragma unroll 1
    for (int ksi = 1; ksi < 16; ksi++) {
        stage(cur ^ 1, ksi);  // issue next tile (other buffer) BEFORE compute
        compute(cur);
        __syncthreads();      // single per-iter drain after MFMAs
        cur ^= 1;
    }
    compute(cur);             // last tile, no prefetch

    // ---- epilogue: relu * gate
    // C/D layout (m89/m91): col = lane&15, row = (lane>>4)*4 + reg
    const int col0 = nt * 128 + wn * 64 + fm;
#pragma unroll
    for (int i = 0; i < 4; i++) {
        int rbase = wm * 64 + i * 16 + kq * 4;
#pragma unroll
        for (int j = 0; j < 4; j++) {
            int col = col0 + j * 16;
#pragma unroll
            for (int r = 0; r < 4; r++) {
                int row = rbase + r;
                if (row < valid) {
                    float v = acc[i][j][r];
                    v = fmaxf(v, 0.f) * gate_s[row];
                    if (MODE == 0)
                        atomicAdd(outc + (size_t)tok_s[row] * DIM + col, v);
                    else
                        outc[(size_t)crow_s[row] * DIM + col] = v;  // unique cell
                }
            }
        }
    }
}

// ---------------------------------------------------------------------------
// Phase 4 (fast2 path): combine. out[n] = sum over k of gated comb rows.
// One block per token row; 256 threads x float4 = 1024 floats.
// ---------------------------------------------------------------------------
__global__ __launch_bounds__(256) void combine_kernel(
    const float* __restrict__ comb, const int* __restrict__ slot_of,
    float* __restrict__ out)
{
    const int n = blockIdx.x;
    const int d = threadIdx.x;
    const int s0 = slot_of[n];
    const int s1 = slot_of[N_TOK + n];
    float4 r = make_float4(0.f, 0.f, 0.f, 0.f);
    if (s0 < CAPACITY) {
        float4 v = ((const float4*)(comb + (size_t)n * DIM))[d];
        r.x = v.x; r.y = v.y; r.z = v.z; r.w = v.w;
    }
    if (s1 < CAPACITY) {
        float4 v = ((const float4*)(comb + ((size_t)N_TOK + n) * DIM))[d];
        r.x += v.x; r.y += v.y; r.z += v.z; r.w += v.w;
    }
    ((float4*)(out + (size_t)n * DIM))[d] = r;
}

// ---------------------------------------------------------------------------
// Legacy Phase 3 (fallback if workspace cannot hold WeB): bf16 MFMA with
// in-loop fp32 B staging, atomic epilogue.
// ---------------------------------------------------------------------------
#define MT 128
#define NT 128
#define BK 32
#define LDA 36   // shorts per LDS row: 32 + 4 pad

__global__ __launch_bounds__(256) void moe_gemm(
    const unsigned short* __restrict__ xb, const float* __restrict__ We,
    const int* __restrict__ list_tok, const float* __restrict__ list_gate,
    const int* __restrict__ cntc, float* __restrict__ out)
{
    const int bid = blockIdx.x;
    const int e   = bid / 40;
    const int rem = bid % 40;
    const int mt  = rem >> 3;
    const int nt  = rem & 7;
    const int cnt = cntc[e];
    if (mt * MT >= cnt) return;
    int valid = cnt - mt * MT; if (valid > MT) valid = MT;

    __shared__ unsigned short As[MT * LDA];
    __shared__ unsigned short Bs[NT * LDA];   // B^T: [n][k]
    __shared__ int   tok_s[MT];
    __shared__ float gate_s[MT];

    const int tid = threadIdx.x;
    if (tid < MT) {
        int slot = mt * MT + tid;
        bool v = tid < valid;
        int raw = v ? list_tok[e * CAPACITY + slot] : list_tok[e * CAPACITY];
        tok_s[tid]  = raw & 0x3FFF;
        gate_s[tid] = v ? list_gate[e * CAPACITY + slot] : 0.f;
    }
    __syncthreads();

    const int arow = tid >> 1, ah = tid & 1;
    const unsigned short* aptr = xb + (size_t)tok_s[arow] * DIM + ah * 16;
    const int bn0 = (tid & 31) * 4;
    const int bkr = (tid >> 5) * 4;
    const float* bptr = We + (size_t)e * DIM * DIM + (size_t)bkr * DIM + nt * NT + bn0;

    f32x4 acc[4][4];
#pragma unroll
    for (int i = 0; i < 4; i++)
#pragma unroll
        for (int j = 0; j < 4; j++) acc[i][j] = (f32x4){0.f, 0.f, 0.f, 0.f};

    const int lane = tid & 63, wave = tid >> 6;
    const int wm = wave >> 1, wn = wave & 1;
    const int fm = lane & 15, kq = lane >> 4;

    for (int ks = 0; ks < DIM; ks += BK) {
        __syncthreads();
        uint4 a0 = *(const uint4*)(aptr + ks);
        uint4 a1 = *(const uint4*)(aptr + ks + 8);
        {
            unsigned short* d = &As[arow * LDA + ah * 16];
            *(uint2*)(d + 0)  = make_uint2(a0.x, a0.y);
            *(uint2*)(d + 4)  = make_uint2(a0.z, a0.w);
            *(uint2*)(d + 8)  = make_uint2(a1.x, a1.y);
            *(uint2*)(d + 12) = make_uint2(a1.z, a1.w);
        }
        {
            float4 b[4];
#pragma unroll
            for (int j = 0; j < 4; j++)
                b[j] = *(const float4*)(bptr + (size_t)(ks + j) * DIM);
            union { float4 v; float f[4]; } u0, u1, u2, u3;
            u0.v = b[0]; u1.v = b[1]; u2.v = b[2]; u3.v = b[3];
#pragma unroll
            for (int cc = 0; cc < 4; cc++) {
                unsigned int lo = (unsigned int)f2bf(u0.f[cc]) | ((unsigned int)f2bf(u1.f[cc]) << 16);
                unsigned int hi = (unsigned int)f2bf(u2.f[cc]) | ((unsigned int)f2bf(u3.f[cc]) << 16);
                *(uint2*)&Bs[(bn0 + cc) * LDA + bkr] = make_uint2(lo, hi);
            }
        }
        __syncthreads();
        union { uint2 u[2]; bf16x8 v; } fa[4], fb[4];
#pragma unroll
        for (int i = 0; i < 4; i++) {
            const unsigned short* s = &As[(wm * 64 + i * 16 + fm) * LDA + kq * 8];
            fa[i].u[0] = *(const uint2*)(s);
            fa[i].u[1] = *(const uint2*)(s + 4);
        }
#pragma unroll
        for (int j = 0; j < 4; j++) {
            const unsigned short* s = &Bs[(wn * 64 + j * 16 + fm) * LDA + kq * 8];
            fb[j].u[0] = *(const uint2*)(s);
            fb[j].u[1] = *(const uint2*)(s + 4);
        }
#pragma unroll
        for (int i = 0; i < 4; i++)
#pragma unroll
            for (int j = 0; j < 4; j++)
                acc[i][j] = __builtin_amdgcn_mfma_f32_16x16x32_bf16(
                    fa[i].v, fb[j].v, acc[i][j], 0, 0, 0);
    }

    const int col0 = nt * NT + wn * 64 + fm;
#pragma unroll
    for (int i = 0; i < 4; i++) {
        int rbase = wm * 64 + i * 16 + kq * 4;
#pragma unroll
        for (int j = 0; j < 4; j++) {
            int col = col0 + j * 16;
#pragma unroll
            for (int r = 0; r < 4; r++) {
                int row = rbase + r;
                if (row < valid) {
                    float v = acc[i][j][r];
                    v = fmaxf(v, 0.f) * gate_s[row];
                    atomicAdd(out + (size_t)tok_s[row] * DIM + col, v);
                }
            }
        }
    }
}

// ---------------------------------------------------------------------------
extern "C" void kernel_launch(void* const* d_in, const int* in_sizes, int n_in,
                              void* d_out, int out_size, void* d_ws, size_t ws_size,
                              hipStream_t stream)
{
    const float* x  = (const float*)d_in[0];
    const float* Wr = (const float*)d_in[1];
    const float* br = (const float*)d_in[2];
    const float* We = (const float*)d_in[3];
    float* out = (float*)d_out;

    char* ws = (char*)d_ws;
    size_t off = 0;
    unsigned short* xb = (unsigned short*)(ws + off); off += (size_t)N_TOK * DIM * 2;
    int*   top2i     = (int*)(ws + off);   off += (size_t)N_TOK * 2 * 4;
    float* gates2    = (float*)(ws + off); off += (size_t)N_TOK * 2 * 4;
    int*   hist      = (int*)(ws + off);   off += 128 * NEXP * 4;
    int*   cntc      = (int*)(ws + off);   off += NEXP * 4;
    int*   list_tok  = (int*)(ws + off);   off += NEXP * CAPACITY * 4;
    float* list_gate = (float*)(ws + off); off += NEXP * CAPACITY * 4;
    int*   slot_of   = (int*)(ws + off);   off += (size_t)N_TOK * 2 * 4;
    off = (off + 255) & ~(size_t)255;
    unsigned short* WeB = (unsigned short*)(ws + off);
    size_t need = off + (size_t)NEXP * DIM * DIM * 2;     // +128 MB bf16 We
    size_t off2 = (need + 255) & ~(size_t)255;
    float* comb = (float*)(ws + off2);
    size_t need2 = off2 + (size_t)N_TOK * 2 * DIM * 4;    // +128 MB f32 comb

    const bool fast2 = ws_size >= need2;   // WeB + comb: atomic-free path
    const bool fast  = ws_size >= need;    // WeB only: atomic path

    hipMemsetAsync(hist, 0, 128 * NEXP * 4, stream);
    if (fast2) {
        // router (256) + We-convert (8192); no out-zero role needed
        router_convert<<<8448, 256, 0, stream>>>(x, Wr, br, We, xb, WeB,
                                                 top2i, gates2, hist, out);
        rank_kernel<<<128, 64, 0, stream>>>(top2i, gates2, hist,
                                            list_tok, list_gate, cntc, slot_of);
        moe_gemm3t<1><<<NEXP * 40, 256, 0, stream>>>(xb, WeB, list_tok,
                                                     list_gate, cntc, comb);
        combine_kernel<<<N_TOK, 256, 0, stream>>>(comb, slot_of, out);
    } else if (fast) {
        router_convert<<<8960, 256, 0, stream>>>(x, Wr, br, We, xb, WeB,
                                                 top2i, gates2, hist, out);
        rank_kernel<<<128, 64, 0, stream>>>(top2i, gates2, hist,
                                            list_tok, list_gate, cntc, slot_of);
        moe_gemm3t<0><<<NEXP * 40, 256, 0, stream>>>(xb, WeB, list_tok,
                                                     list_gate, cntc, out);
    } else {
        hipMemsetAsync(out, 0, (size_t)N_TOK * DIM * 4, stream);
        router_convert<<<256, 256, 0, stream>>>(x, Wr, br, We, xb, xb,
                                                top2i, gates2, hist, out);
        rank_kernel<<<128, 64, 0, stream>>>(top2i, gates2, hist,
                                            list_tok, list_gate, cntc, slot_of);
        moe_gemm<<<NEXP * 40, 256, 0, stream>>>(xb, We, list_tok, list_gate,
                                                cntc, out);
    }
}